// Round 2
// baseline (706.081 us; speedup 1.0000x reference)
//
#include <hip/hip_runtime.h>

#define FEPS 1e-12f

__device__ __forceinline__ void top3_insert(float val, int idx,
                                            float& v0, float& v1, float& v2,
                                            int& i0, int& i1, int& i2) {
    if (val > v0)      { v2 = v1; i2 = i1; v1 = v0; i1 = i0; v0 = val; i0 = idx; }
    else if (val > v1) { v2 = v1; i2 = i1; v1 = val; i1 = idx; }
    else if (val > v2) { v2 = val; i2 = idx; }
}

// Split-K GEMV, float4 columns: out[j..j+3] += sum_{i in chunk} f(v[i]) * W[i,j..j+3]
// W row-major (R x C). grid = (C/1024, R/chunk), block = 256. out pre-zeroed.
// (round-0 form: runtime chunk, compiler schedules the pipeline itself)
template<int RELU>
__global__ void gemv_atomic4(const float* __restrict__ v,
                             const float* __restrict__ W,
                             const float* __restrict__ bias,
                             float* __restrict__ out,
                             int C, int chunk) {
    int j = (blockIdx.x * 256 + threadIdx.x) * 4;
    int i0 = blockIdx.y * chunk;
    float4 acc = make_float4(0.f, 0.f, 0.f, 0.f);
    for (int i = i0; i < i0 + chunk; ++i) {
        float vi = v[i];
        if (RELU) vi = fmaxf(vi, 0.f);
        float4 w = *(const float4*)(W + (size_t)i * C + j);
        acc.x += vi * w.x; acc.y += vi * w.y;
        acc.z += vi * w.z; acc.w += vi * w.w;
    }
    if (blockIdx.y == 0) {
        float4 b = *(const float4*)(bias + j);
        acc.x += b.x; acc.y += b.y; acc.z += b.z; acc.w += b.w;
    }
    atomicAdd(&out[j + 0], acc.x);
    atomicAdd(&out[j + 1], acc.y);
    atomicAdd(&out[j + 2], acc.z);
    atomicAdd(&out[j + 3], acc.w);
}

// Each block: 32 key rows (wave w -> rows base+w*8 .. +7), round-0 inner body.
// weighted[m] = (q.k_m) * imp[m] / max(||k_m||,eps)  (÷||q|| deferred — positive
// scalar, order-preserving). Block top-3 -> cand arrays; LAST block (device
// ticket) does global top-3 + softmax + values gather + zeroes `out`.
__global__ void sims_top3_fused(const float* __restrict__ q,
                                const float* __restrict__ keys,
                                const float* __restrict__ imp,
                                const float* __restrict__ values,
                                float* __restrict__ cand_val,
                                int* __restrict__ cand_idx,
                                unsigned* __restrict__ ctr,
                                float* __restrict__ retr,     // = comb + 2048
                                float* __restrict__ out) {    // zeroed here (2048)
    __shared__ float qs[1024];
    __shared__ float wv[4 * 3];
    __shared__ int   wi[4 * 3];
    __shared__ float s_red[4];
    __shared__ float s_attn[3];
    __shared__ int   s_idx[3];
    __shared__ int   s_last;
    int t = threadIdx.x;
    #pragma unroll
    for (int p = 0; p < 4; ++p) qs[t + 256 * p] = q[t + 256 * p];
    __syncthreads();
    int wave = t >> 6, lane = t & 63;
    const float4* q4 = (const float4*)qs;
    float4 qv[4];
    #pragma unroll
    for (int p = 0; p < 4; ++p) qv[p] = q4[lane + 64 * p];

    float v0 = -INFINITY, v1 = -INFINITY, v2 = -INFINITY;
    int   i0 = -1, i1 = -1, i2 = -1;
    int mbase = blockIdx.x * 32 + wave * 8;
    for (int r = 0; r < 8; ++r) {
        int m = mbase + r;
        const float4* krow = (const float4*)(keys + (size_t)m * 1024);
        float dot = 0.f, sq = 0.f;
        #pragma unroll
        for (int p = 0; p < 4; ++p) {
            float4 k = krow[lane + 64 * p];
            dot += k.x * qv[p].x + k.y * qv[p].y + k.z * qv[p].z + k.w * qv[p].w;
            sq  += k.x * k.x + k.y * k.y + k.z * k.z + k.w * k.w;
        }
        #pragma unroll
        for (int off = 32; off; off >>= 1) {
            dot += __shfl_down(dot, off);
            sq  += __shfl_down(sq, off);
        }
        if (lane == 0) {
            float val = dot * imp[m] / fmaxf(sqrtf(sq), FEPS);
            top3_insert(val, m, v0, v1, v2, i0, i1, i2);
        }
    }
    if (lane == 0) {
        wv[wave * 3 + 0] = v0; wv[wave * 3 + 1] = v1; wv[wave * 3 + 2] = v2;
        wi[wave * 3 + 0] = i0; wi[wave * 3 + 1] = i1; wi[wave * 3 + 2] = i2;
    }
    __syncthreads();
    if (t == 0) {
        float a0 = -INFINITY, a1 = -INFINITY, a2 = -INFINITY;
        int   b0 = -1, b1 = -1, b2 = -1;
        for (int e = 0; e < 12; ++e)
            top3_insert(wv[e], wi[e], a0, a1, a2, b0, b1, b2);
        int base = blockIdx.x * 3;
        __hip_atomic_store(&cand_val[base + 0], a0, __ATOMIC_RELAXED, __HIP_MEMORY_SCOPE_AGENT);
        __hip_atomic_store(&cand_val[base + 1], a1, __ATOMIC_RELAXED, __HIP_MEMORY_SCOPE_AGENT);
        __hip_atomic_store(&cand_val[base + 2], a2, __ATOMIC_RELAXED, __HIP_MEMORY_SCOPE_AGENT);
        __hip_atomic_store(&cand_idx[base + 0], b0, __ATOMIC_RELAXED, __HIP_MEMORY_SCOPE_AGENT);
        __hip_atomic_store(&cand_idx[base + 1], b1, __ATOMIC_RELAXED, __HIP_MEMORY_SCOPE_AGENT);
        __hip_atomic_store(&cand_idx[base + 2], b2, __ATOMIC_RELAXED, __HIP_MEMORY_SCOPE_AGENT);
        __threadfence();
        unsigned tk = __hip_atomic_fetch_add(ctr, 1u, __ATOMIC_ACQ_REL, __HIP_MEMORY_SCOPE_AGENT);
        s_last = (tk == gridDim.x - 1) ? 1 : 0;
    }
    __syncthreads();
    if (!s_last) return;

    // ---------------- last block: global finalize ----------------
    __threadfence();
    // ||q|| from qs (already staged in LDS)
    float pq = 0.f;
    #pragma unroll
    for (int p = 0; p < 4; ++p) { float x = qs[t + 256 * p]; pq = fmaf(x, x, pq); }
    #pragma unroll
    for (int off = 32; off; off >>= 1) pq += __shfl_down(pq, off);

    // per-thread top-3 over 24 candidates each (coalesced stride-256)
    float c0 = -INFINITY, c1 = -INFINITY, c2 = -INFINITY;
    int   d0 = -1, d1 = -1, d2 = -1;
    #pragma unroll
    for (int kk = 0; kk < 24; ++kk) {
        int c = t + (kk << 8);
        float val = __hip_atomic_load(&cand_val[c], __ATOMIC_RELAXED, __HIP_MEMORY_SCOPE_AGENT);
        int   idx = __hip_atomic_load(&cand_idx[c], __ATOMIC_RELAXED, __HIP_MEMORY_SCOPE_AGENT);
        top3_insert(val, idx, c0, c1, c2, d0, d1, d2);
    }
    // wave-level merge of top-3 triples
    #pragma unroll
    for (int off = 32; off; off >>= 1) {
        float u0 = __shfl_down(c0, off), u1 = __shfl_down(c1, off), u2 = __shfl_down(c2, off);
        int   j0 = __shfl_down(d0, off), j1 = __shfl_down(d1, off), j2 = __shfl_down(d2, off);
        top3_insert(u0, j0, c0, c1, c2, d0, d1, d2);
        top3_insert(u1, j1, c0, c1, c2, d0, d1, d2);
        top3_insert(u2, j2, c0, c1, c2, d0, d1, d2);
    }
    if (lane == 0) {
        wv[wave * 3 + 0] = c0; wv[wave * 3 + 1] = c1; wv[wave * 3 + 2] = c2;
        wi[wave * 3 + 0] = d0; wi[wave * 3 + 1] = d1; wi[wave * 3 + 2] = d2;
        s_red[wave] = pq;
    }
    __syncthreads();
    if (t == 0) {
        float a0 = -INFINITY, a1 = -INFINITY, a2 = -INFINITY;
        int   b0 = -1, b1 = -1, b2 = -1;
        for (int e = 0; e < 12; ++e)
            top3_insert(wv[e], wi[e], a0, a1, a2, b0, b1, b2);
        float qden = fmaxf(sqrtf(s_red[0] + s_red[1] + s_red[2] + s_red[3]), FEPS);
        float tv0 = a0 / qden, tv1 = a1 / qden, tv2 = a2 / qden;
        float mx = fmaxf(tv0, fmaxf(tv1, tv2));
        float e0 = expf(tv0 - mx), e1 = expf(tv1 - mx), e2 = expf(tv2 - mx);
        float sum = e0 + e1 + e2;
        s_attn[0] = e0 / sum; s_attn[1] = e1 / sum; s_attn[2] = e2 / sum;
        s_idx[0] = b0; s_idx[1] = b1; s_idx[2] = b2;
    }
    __syncthreads();

    // retrieved[1024] = attn @ values[top_idx]
    #pragma unroll
    for (int p = 0; p < 4; ++p) {
        int col = t + 256 * p;
        float r = s_attn[0] * values[(size_t)s_idx[0] * 1024 + col]
                + s_attn[1] * values[(size_t)s_idx[1] * 1024 + col]
                + s_attn[2] * values[(size_t)s_idx[2] * 1024 + col];
        retr[col] = r;
    }
    // zero out[2048] for the following atomic Wout GEMV (replaces host memset)
    #pragma unroll
    for (int p = 0; p < 8; ++p) out[t + 256 * p] = 0.0f;
}

extern "C" void kernel_launch(void* const* d_in, const int* in_sizes, int n_in,
                              void* d_out, int out_size, void* d_ws, size_t ws_size,
                              hipStream_t stream) {
    const float* x      = (const float*)d_in[0];
    const float* W1     = (const float*)d_in[1];
    const float* b1     = (const float*)d_in[2];
    const float* W2     = (const float*)d_in[3];
    const float* b2     = (const float*)d_in[4];
    const float* Wq     = (const float*)d_in[5];
    const float* bq     = (const float*)d_in[6];
    const float* Wout   = (const float*)d_in[7];
    const float* bout   = (const float*)d_in[8];
    const float* keys   = (const float*)d_in[9];
    const float* values = (const float*)d_in[10];
    const float* imp    = (const float*)d_in[11];
    float* out = (float*)d_out;
    float* ws  = (float*)d_ws;

    // ws layout (floats):
    // [0,2048)        h1
    // [2048,5120)     comb = last_hidden (2048) | retrieved (1024)
    // [5120,6144)     q
    // [6144]          done-counter (unsigned)
    // [6160,12304)    cand_val (6144)
    // [12304,18448)   cand_idx (6144 ints)
    float*    h1       = ws;
    float*    comb     = ws + 2048;
    float*    retr     = ws + 4096;
    float*    q        = ws + 5120;
    unsigned* ctr      = (unsigned*)(ws + 6144);
    float*    cand_val = ws + 6160;
    int*      cand_idx = (int*)(ws + 12304);

    const float* xlast = x + (size_t)(4096 - 1) * 2048;  // only last position matters

    // zero atomic accumulators (h1, comb, q) + counter. d_out zeroed in-kernel.
    hipMemsetAsync(d_ws, 0, 6160 * sizeof(float), stream);

    // h1 = xlast @ W1 + b1                       (16 MB)
    gemv_atomic4<0><<<dim3(2, 128), 256, 0, stream>>>(xlast, W1, b1, h1, 2048, 16);
    // last_hidden = relu(h1) @ W2 + b2           (16 MB)
    gemv_atomic4<1><<<dim3(2, 128), 256, 0, stream>>>(h1, W2, b2, comb, 2048, 16);
    // q = last_hidden @ Wq + bq                  (8 MB)
    gemv_atomic4<0><<<dim3(1, 128), 256, 0, stream>>>(comb, Wq, bq, q, 1024, 16);
    // sims + per-block top-3 over 65536 keys (256 MB — dominant), 2048 blocks
    // (8 blocks/CU -> 32 waves/CU) + fused global top-3 / softmax / gather /
    // out-zeroing in last block
    sims_top3_fused<<<2048, 256, 0, stream>>>(q, keys, imp, values,
                                              cand_val, cand_idx, ctr, retr, out);
    // out = comb @ Wout + bout                   (24 MB)
    gemv_atomic4<0><<<dim3(2, 128), 256, 0, stream>>>(comb, Wout, bout, out, 2048, 24);
}

// Round 3
// 698.928 us; speedup vs baseline: 1.0102x; 1.0102x over previous
//
#include <hip/hip_runtime.h>

#define FEPS 1e-12f

__device__ __forceinline__ void top3_insert(float val, int idx,
                                            float& v0, float& v1, float& v2,
                                            int& i0, int& i1, int& i2) {
    if (val > v0)      { v2 = v1; i2 = i1; v1 = v0; i1 = i0; v0 = val; i0 = idx; }
    else if (val > v1) { v2 = v1; i2 = i1; v1 = val; i1 = idx; }
    else if (val > v2) { v2 = val; i2 = idx; }
}

// Split-K GEMV, float4 columns: out[j..j+3] += sum_{i in chunk} f(v[i]) * W[i,j..j+3]
// W row-major (R x C). grid = (C/1024, R/chunk), block = 256. out pre-zeroed.
// (round-0 form: runtime chunk, compiler schedules the pipeline itself)
template<int RELU>
__global__ void gemv_atomic4(const float* __restrict__ v,
                             const float* __restrict__ W,
                             const float* __restrict__ bias,
                             float* __restrict__ out,
                             int C, int chunk) {
    int j = (blockIdx.x * 256 + threadIdx.x) * 4;
    int i0 = blockIdx.y * chunk;
    float4 acc = make_float4(0.f, 0.f, 0.f, 0.f);
    for (int i = i0; i < i0 + chunk; ++i) {
        float vi = v[i];
        if (RELU) vi = fmaxf(vi, 0.f);
        float4 w = *(const float4*)(W + (size_t)i * C + j);
        acc.x += vi * w.x; acc.y += vi * w.y;
        acc.z += vi * w.z; acc.w += vi * w.w;
    }
    if (blockIdx.y == 0) {
        float4 b = *(const float4*)(bias + j);
        acc.x += b.x; acc.y += b.y; acc.z += b.z; acc.w += b.w;
    }
    atomicAdd(&out[j + 0], acc.x);
    atomicAdd(&out[j + 1], acc.y);
    atomicAdd(&out[j + 2], acc.z);
    atomicAdd(&out[j + 3], acc.w);
}

// One THREAD per key row (no cross-lane reduce in the hot loop).
// 64 threads/block (1 wave), 1024 blocks -> 65536 rows. Each lane walks its
// own 4KB row in 128B chunks; q broadcast from LDS (uniform addr). Per-block
// column rotation decorrelates the 4KB power-of-2 stride across blocks.
// Block top-3 via one wave butterfly; LAST block (device ticket) does global
// top-3 + softmax + values gather + zeroes `out`.
__global__ __launch_bounds__(64)
void sims_top3_rows(const float* __restrict__ q,
                    const float* __restrict__ keys,
                    const float* __restrict__ imp,
                    const float* __restrict__ values,
                    float* __restrict__ cand_val,
                    int* __restrict__ cand_idx,
                    unsigned* __restrict__ ctr,
                    float* __restrict__ retr,     // = comb + 2048
                    float* __restrict__ out) {    // zeroed here (2048)
    __shared__ float qs[1024];
    int t = threadIdx.x;   // == lane (single wave)
    #pragma unroll
    for (int p = 0; p < 4; ++p)
        *(float4*)(qs + (t + 64 * p) * 4) = *(const float4*)(q + (t + 64 * p) * 4);
    __syncthreads();

    int m = blockIdx.x * 64 + t;
    const float* krow = keys + (size_t)m * 1024;
    int c0 = (blockIdx.x * 5) & 31;   // per-block column rotation
    float dot0 = 0.f, dot1 = 0.f, sq0 = 0.f, sq1 = 0.f;
    #pragma unroll 2
    for (int s = 0; s < 32; ++s) {
        int c = (c0 + s) & 31;
        const float4* kc = (const float4*)(krow + c * 32);
        const float4* qc = (const float4*)(qs + c * 32);
        float4 k[8], qv[8];
        #pragma unroll
        for (int j = 0; j < 8; ++j) k[j] = kc[j];
        #pragma unroll
        for (int j = 0; j < 8; ++j) qv[j] = qc[j];
        #pragma unroll
        for (int j = 0; j < 8; j += 2) {
            dot0 += k[j].x * qv[j].x + k[j].y * qv[j].y
                  + k[j].z * qv[j].z + k[j].w * qv[j].w;
            sq0  += k[j].x * k[j].x + k[j].y * k[j].y
                  + k[j].z * k[j].z + k[j].w * k[j].w;
            dot1 += k[j+1].x * qv[j+1].x + k[j+1].y * qv[j+1].y
                  + k[j+1].z * qv[j+1].z + k[j+1].w * qv[j+1].w;
            sq1  += k[j+1].x * k[j+1].x + k[j+1].y * k[j+1].y
                  + k[j+1].z * k[j+1].z + k[j+1].w * k[j+1].w;
        }
    }
    float val = (dot0 + dot1) * imp[m] / fmaxf(sqrtf(sq0 + sq1), FEPS);

    // wave top-3 butterfly (once per block)
    float v0 = val, v1 = -INFINITY, v2 = -INFINITY;
    int   i0 = m,   i1 = -1, i2 = -1;
    #pragma unroll
    for (int off = 32; off; off >>= 1) {
        float u0 = __shfl_down(v0, off), u1 = __shfl_down(v1, off), u2 = __shfl_down(v2, off);
        int   j0 = __shfl_down(i0, off), j1 = __shfl_down(i1, off), j2 = __shfl_down(i2, off);
        top3_insert(u0, j0, v0, v1, v2, i0, i1, i2);
        top3_insert(u1, j1, v0, v1, v2, i0, i1, i2);
        top3_insert(u2, j2, v0, v1, v2, i0, i1, i2);
    }

    int last = 0;
    if (t == 0) {
        int base = blockIdx.x * 3;
        __hip_atomic_store(&cand_val[base + 0], v0, __ATOMIC_RELAXED, __HIP_MEMORY_SCOPE_AGENT);
        __hip_atomic_store(&cand_val[base + 1], v1, __ATOMIC_RELAXED, __HIP_MEMORY_SCOPE_AGENT);
        __hip_atomic_store(&cand_val[base + 2], v2, __ATOMIC_RELAXED, __HIP_MEMORY_SCOPE_AGENT);
        __hip_atomic_store(&cand_idx[base + 0], i0, __ATOMIC_RELAXED, __HIP_MEMORY_SCOPE_AGENT);
        __hip_atomic_store(&cand_idx[base + 1], i1, __ATOMIC_RELAXED, __HIP_MEMORY_SCOPE_AGENT);
        __hip_atomic_store(&cand_idx[base + 2], i2, __ATOMIC_RELAXED, __HIP_MEMORY_SCOPE_AGENT);
        __threadfence();
        unsigned tk = __hip_atomic_fetch_add(ctr, 1u, __ATOMIC_ACQ_REL, __HIP_MEMORY_SCOPE_AGENT);
        last = (tk == gridDim.x - 1) ? 1 : 0;
    }
    last = __shfl(last, 0);
    if (!last) return;

    // ---------------- last block (one wave): global finalize ----------------
    __threadfence();
    // ||q|| from qs
    float pq = 0.f;
    #pragma unroll
    for (int p = 0; p < 16; ++p) { float x = qs[t + 64 * p]; pq = fmaf(x, x, pq); }
    #pragma unroll
    for (int off = 32; off; off >>= 1) pq += __shfl_down(pq, off);

    // per-lane top-3 over 48 candidates each (coalesced stride-64)
    float c0v = -INFINITY, c1v = -INFINITY, c2v = -INFINITY;
    int   d0 = -1, d1 = -1, d2 = -1;
    for (int kk = 0; kk < 48; ++kk) {
        int c = t + (kk << 6);
        float cv = __hip_atomic_load(&cand_val[c], __ATOMIC_RELAXED, __HIP_MEMORY_SCOPE_AGENT);
        int   ci = __hip_atomic_load(&cand_idx[c], __ATOMIC_RELAXED, __HIP_MEMORY_SCOPE_AGENT);
        top3_insert(cv, ci, c0v, c1v, c2v, d0, d1, d2);
    }
    #pragma unroll
    for (int off = 32; off; off >>= 1) {
        float u0 = __shfl_down(c0v, off), u1 = __shfl_down(c1v, off), u2 = __shfl_down(c2v, off);
        int   j0 = __shfl_down(d0, off),  j1 = __shfl_down(d1, off),  j2 = __shfl_down(d2, off);
        top3_insert(u0, j0, c0v, c1v, c2v, d0, d1, d2);
        top3_insert(u1, j1, c0v, c1v, c2v, d0, d1, d2);
        top3_insert(u2, j2, c0v, c1v, c2v, d0, d1, d2);
    }

    float attn0 = 0.f, attn1 = 0.f, attn2 = 0.f;
    int   id0 = 0, id1 = 0, id2 = 0;
    if (t == 0) {
        float qden = fmaxf(sqrtf(pq), FEPS);
        float tv0 = c0v / qden, tv1 = c1v / qden, tv2 = c2v / qden;
        float mx = fmaxf(tv0, fmaxf(tv1, tv2));
        float e0 = expf(tv0 - mx), e1 = expf(tv1 - mx), e2 = expf(tv2 - mx);
        float sum = e0 + e1 + e2;
        attn0 = e0 / sum; attn1 = e1 / sum; attn2 = e2 / sum;
        id0 = d0; id1 = d1; id2 = d2;
    }
    attn0 = __shfl(attn0, 0); attn1 = __shfl(attn1, 0); attn2 = __shfl(attn2, 0);
    id0 = __shfl(id0, 0); id1 = __shfl(id1, 0); id2 = __shfl(id2, 0);

    const float4* V0 = (const float4*)(values + (size_t)id0 * 1024);
    const float4* V1 = (const float4*)(values + (size_t)id1 * 1024);
    const float4* V2 = (const float4*)(values + (size_t)id2 * 1024);
    float4* retr4 = (float4*)retr;
    #pragma unroll
    for (int p = 0; p < 4; ++p) {
        int c4 = t + 64 * p;
        float4 a = V0[c4], b = V1[c4], c = V2[c4], r;
        r.x = attn0 * a.x + attn1 * b.x + attn2 * c.x;
        r.y = attn0 * a.y + attn1 * b.y + attn2 * c.y;
        r.z = attn0 * a.z + attn1 * b.z + attn2 * c.z;
        r.w = attn0 * a.w + attn1 * b.w + attn2 * c.w;
        retr4[c4] = r;
    }
    // zero out[2048] for the following atomic Wout GEMV
    float4* out4 = (float4*)out;
    float4 z = make_float4(0.f, 0.f, 0.f, 0.f);
    #pragma unroll
    for (int p = 0; p < 8; ++p) out4[t + 64 * p] = z;
}

extern "C" void kernel_launch(void* const* d_in, const int* in_sizes, int n_in,
                              void* d_out, int out_size, void* d_ws, size_t ws_size,
                              hipStream_t stream) {
    const float* x      = (const float*)d_in[0];
    const float* W1     = (const float*)d_in[1];
    const float* b1     = (const float*)d_in[2];
    const float* W2     = (const float*)d_in[3];
    const float* b2     = (const float*)d_in[4];
    const float* Wq     = (const float*)d_in[5];
    const float* bq     = (const float*)d_in[6];
    const float* Wout   = (const float*)d_in[7];
    const float* bout   = (const float*)d_in[8];
    const float* keys   = (const float*)d_in[9];
    const float* values = (const float*)d_in[10];
    const float* imp    = (const float*)d_in[11];
    float* out = (float*)d_out;
    float* ws  = (float*)d_ws;

    // ws layout (floats):
    // [0,2048)       h1
    // [2048,5120)    comb = last_hidden (2048) | retrieved (1024)
    // [5120,6144)    q
    // [6144]         done-counter (unsigned)
    // [6160,9232)    cand_val (3072)
    // [9232,12304)   cand_idx (3072 ints)
    float*    h1       = ws;
    float*    comb     = ws + 2048;
    float*    retr     = ws + 4096;
    float*    q        = ws + 5120;
    unsigned* ctr      = (unsigned*)(ws + 6144);
    float*    cand_val = ws + 6160;
    int*      cand_idx = (int*)(ws + 9232);

    const float* xlast = x + (size_t)(4096 - 1) * 2048;  // only last position matters

    // zero atomic accumulators (h1, comb, q) + counter. d_out zeroed in-kernel.
    hipMemsetAsync(d_ws, 0, 6160 * sizeof(float), stream);

    // h1 = xlast @ W1 + b1                       (16 MB)
    gemv_atomic4<0><<<dim3(2, 128), 256, 0, stream>>>(xlast, W1, b1, h1, 2048, 16);
    // last_hidden = relu(h1) @ W2 + b2           (16 MB)
    gemv_atomic4<1><<<dim3(2, 128), 256, 0, stream>>>(h1, W2, b2, comb, 2048, 16);
    // q = last_hidden @ Wq + bq                  (8 MB)
    gemv_atomic4<0><<<dim3(1, 128), 256, 0, stream>>>(comb, Wq, bq, q, 1024, 16);
    // sims: one thread per key row, 1024 blocks x 1 wave (256 MB — dominant)
    // + fused global top-3 / softmax / gather / out-zeroing in last block
    sims_top3_rows<<<1024, 64, 0, stream>>>(q, keys, imp, values,
                                            cand_val, cand_idx, ctr, retr, out);
    // out = comb @ Wout + bout                   (24 MB)
    gemv_atomic4<0><<<dim3(2, 128), 256, 0, stream>>>(comb, Wout, bout, out, 2048, 24);
}

// Round 4
// 608.828 us; speedup vs baseline: 1.1597x; 1.1480x over previous
//
#include <hip/hip_runtime.h>

#define FEPS 1e-12f

// Split-K GEMV, float4 columns: out[j..j+3] += sum_{i in chunk} f(v[i]) * W[i,j..j+3]
// W row-major (R x C). grid = (C/1024, R/chunk), block = 256. out pre-zeroed.
template<int RELU>
__global__ void gemv_atomic4(const float* __restrict__ v,
                             const float* __restrict__ W,
                             const float* __restrict__ bias,
                             float* __restrict__ out,
                             int C, int chunk) {
    int j = (blockIdx.x * 256 + threadIdx.x) * 4;
    int i0 = blockIdx.y * chunk;
    float4 acc = make_float4(0.f, 0.f, 0.f, 0.f);
    for (int i = i0; i < i0 + chunk; ++i) {
        float vi = v[i];
        if (RELU) vi = fmaxf(vi, 0.f);
        float4 w = *(const float4*)(W + (size_t)i * C + j);
        acc.x += vi * w.x; acc.y += vi * w.y;
        acc.z += vi * w.z; acc.w += vi * w.w;
    }
    if (blockIdx.y == 0) {
        float4 b = *(const float4*)(bias + j);
        acc.x += b.x; acc.y += b.y; acc.z += b.z; acc.w += b.w;
    }
    atomicAdd(&out[j + 0], acc.x);
    atomicAdd(&out[j + 1], acc.y);
    atomicAdd(&out[j + 2], acc.z);
    atomicAdd(&out[j + 3], acc.w);
}

// Round-0 geometry: block = 256 (4 waves), wave w -> rows base+w*16 .. +15.
// ONE change vs round 0: hand-pipelined 1-deep row prefetch (named scalar
// float4 regs) so row r+1's global loads are in flight during row r's
// FMA + shuffle reduction. weighted[m] = (q.k_m)*imp[m]/max(||k_m||,eps)
// (÷||q|| deferred — positive scalar, order-preserving). Block top-3 out.
__global__ void sims_top3_pf(const float* __restrict__ q,
                             const float* __restrict__ keys,
                             const float* __restrict__ imp,
                             float* __restrict__ cand_val,
                             int* __restrict__ cand_idx) {
    __shared__ float qs[1024];
    __shared__ float wv[4 * 3];
    __shared__ int   wi[4 * 3];
    int t = threadIdx.x;
    #pragma unroll
    for (int p = 0; p < 4; ++p) qs[t + 256 * p] = q[t + 256 * p];
    __syncthreads();
    int wave = t >> 6, lane = t & 63;
    const float4* q4 = (const float4*)qs;
    float4 qv0 = q4[lane];
    float4 qv1 = q4[lane + 64];
    float4 qv2 = q4[lane + 128];
    float4 qv3 = q4[lane + 192];

    float v0 = -INFINITY, v1 = -INFINITY, v2 = -INFINITY;
    int   i0 = -1, i1 = -1, i2 = -1;
    int mbase = blockIdx.x * 64 + wave * 16;

    // prefetch row 0
    const float4* krow = (const float4*)(keys + (size_t)mbase * 1024);
    float4 k0 = krow[lane];
    float4 k1 = krow[lane + 64];
    float4 k2 = krow[lane + 128];
    float4 k3 = krow[lane + 192];
    float  im = imp[mbase];

    #pragma unroll
    for (int r = 0; r < 16; ++r) {
        // issue next row's loads BEFORE consuming this row
        float4 n0, n1, n2, n3;
        float  nim;
        if (r < 15) {
            const float4* nrow = (const float4*)(keys + (size_t)(mbase + r + 1) * 1024);
            n0 = nrow[lane];
            n1 = nrow[lane + 64];
            n2 = nrow[lane + 128];
            n3 = nrow[lane + 192];
            nim = imp[mbase + r + 1];
        }
        float dot = k0.x * qv0.x + k0.y * qv0.y + k0.z * qv0.z + k0.w * qv0.w
                  + k1.x * qv1.x + k1.y * qv1.y + k1.z * qv1.z + k1.w * qv1.w
                  + k2.x * qv2.x + k2.y * qv2.y + k2.z * qv2.z + k2.w * qv2.w
                  + k3.x * qv3.x + k3.y * qv3.y + k3.z * qv3.z + k3.w * qv3.w;
        float sq  = k0.x * k0.x + k0.y * k0.y + k0.z * k0.z + k0.w * k0.w
                  + k1.x * k1.x + k1.y * k1.y + k1.z * k1.z + k1.w * k1.w
                  + k2.x * k2.x + k2.y * k2.y + k2.z * k2.z + k2.w * k2.w
                  + k3.x * k3.x + k3.y * k3.y + k3.z * k3.z + k3.w * k3.w;
        #pragma unroll
        for (int off = 32; off; off >>= 1) {
            dot += __shfl_down(dot, off);
            sq  += __shfl_down(sq, off);
        }
        if (lane == 0) {
            float val = dot * im / fmaxf(sqrtf(sq), FEPS);
            int m = mbase + r;
            if (val > v0)      { v2 = v1; i2 = i1; v1 = v0; i1 = i0; v0 = val; i0 = m; }
            else if (val > v1) { v2 = v1; i2 = i1; v1 = val; i1 = m; }
            else if (val > v2) { v2 = val; i2 = m; }
        }
        k0 = n0; k1 = n1; k2 = n2; k3 = n3; im = nim;
    }
    if (lane == 0) {
        wv[wave * 3 + 0] = v0; wv[wave * 3 + 1] = v1; wv[wave * 3 + 2] = v2;
        wi[wave * 3 + 0] = i0; wi[wave * 3 + 1] = i1; wi[wave * 3 + 2] = i2;
    }
    __syncthreads();
    if (t == 0) {
        float a0 = -INFINITY, a1 = -INFINITY, a2 = -INFINITY;
        int   b0 = -1, b1 = -1, b2 = -1;
        for (int e = 0; e < 12; ++e) {
            float val = wv[e]; int idx = wi[e];
            if (val > a0)      { a2 = a1; b2 = b1; a1 = a0; b1 = b0; a0 = val; b0 = idx; }
            else if (val > a1) { a2 = a1; b2 = b1; a1 = val; b1 = idx; }
            else if (val > a2) { a2 = val; b2 = idx; }
        }
        cand_val[blockIdx.x * 3 + 0] = a0; cand_idx[blockIdx.x * 3 + 0] = b0;
        cand_val[blockIdx.x * 3 + 1] = a1; cand_idx[blockIdx.x * 3 + 1] = b1;
        cand_val[blockIdx.x * 3 + 2] = a2; cand_idx[blockIdx.x * 3 + 2] = b2;
    }
}

// One block, 1024 threads: ||q||, top-3 of 3072 candidates, softmax,
// gather 3 rows of values -> retrieved[1024].  (round-0 verbatim)
__global__ void finalize_retrieve(const float* __restrict__ q,
                                  const float* __restrict__ cand_val,
                                  const int* __restrict__ cand_idx,
                                  const float* __restrict__ values,
                                  float* __restrict__ retrieved) {
    __shared__ float red[1024];
    __shared__ float mv[3 * 1024];
    __shared__ int   mi[3 * 1024];
    __shared__ float s_attn[3];
    __shared__ int   s_idx[3];
    __shared__ float s_qden;
    int t = threadIdx.x;

    float qv = q[t];
    red[t] = qv * qv;
    __syncthreads();
    for (int s = 512; s > 0; s >>= 1) {
        if (t < s) red[t] += red[t + s];
        __syncthreads();
    }
    if (t == 0) s_qden = fmaxf(sqrtf(red[0]), FEPS);

    float v0 = -INFINITY, v1 = -INFINITY, v2 = -INFINITY;
    int   i0 = -1, i1 = -1, i2 = -1;
    #pragma unroll
    for (int k = 0; k < 3; ++k) {
        int c = t + (k << 10);
        float val = cand_val[c];
        int   idx = cand_idx[c];
        if (val > v0)      { v2 = v1; i2 = i1; v1 = v0; i1 = i0; v0 = val; i0 = idx; }
        else if (val > v1) { v2 = v1; i2 = i1; v1 = val; i1 = idx; }
        else if (val > v2) { v2 = val; i2 = idx; }
    }
    mv[t * 3 + 0] = v0; mv[t * 3 + 1] = v1; mv[t * 3 + 2] = v2;
    mi[t * 3 + 0] = i0; mi[t * 3 + 1] = i1; mi[t * 3 + 2] = i2;
    __syncthreads();

    for (int s = 512; s > 0; s >>= 1) {
        if (t < s) {
            float a0 = mv[t * 3], a1 = mv[t * 3 + 1], a2 = mv[t * 3 + 2];
            int   b0 = mi[t * 3], b1 = mi[t * 3 + 1], b2 = mi[t * 3 + 2];
            #pragma unroll
            for (int e = 0; e < 3; ++e) {
                float val = mv[(t + s) * 3 + e];
                int   idx = mi[(t + s) * 3 + e];
                if (val > a0)      { a2 = a1; b2 = b1; a1 = a0; b1 = b0; a0 = val; b0 = idx; }
                else if (val > a1) { a2 = a1; b2 = b1; a1 = val; b1 = idx; }
                else if (val > a2) { a2 = val; b2 = idx; }
            }
            mv[t * 3] = a0; mv[t * 3 + 1] = a1; mv[t * 3 + 2] = a2;
            mi[t * 3] = b0; mi[t * 3 + 1] = b1; mi[t * 3 + 2] = b2;
        }
        __syncthreads();
    }

    if (t == 0) {
        float qden = s_qden;
        float tv0 = mv[0] / qden, tv1 = mv[1] / qden, tv2 = mv[2] / qden;
        float mx = fmaxf(tv0, fmaxf(tv1, tv2));
        float e0 = expf(tv0 - mx), e1 = expf(tv1 - mx), e2 = expf(tv2 - mx);
        float sum = e0 + e1 + e2;
        s_attn[0] = e0 / sum; s_attn[1] = e1 / sum; s_attn[2] = e2 / sum;
        s_idx[0] = mi[0]; s_idx[1] = mi[1]; s_idx[2] = mi[2];
    }
    __syncthreads();

    float r = 0.0f;
    #pragma unroll
    for (int e = 0; e < 3; ++e)
        r += s_attn[e] * values[(size_t)s_idx[e] * 1024 + t];
    retrieved[t] = r;
}

extern "C" void kernel_launch(void* const* d_in, const int* in_sizes, int n_in,
                              void* d_out, int out_size, void* d_ws, size_t ws_size,
                              hipStream_t stream) {
    const float* x      = (const float*)d_in[0];
    const float* W1     = (const float*)d_in[1];
    const float* b1     = (const float*)d_in[2];
    const float* W2     = (const float*)d_in[3];
    const float* b2     = (const float*)d_in[4];
    const float* Wq     = (const float*)d_in[5];
    const float* bq     = (const float*)d_in[6];
    const float* Wout   = (const float*)d_in[7];
    const float* bout   = (const float*)d_in[8];
    const float* keys   = (const float*)d_in[9];
    const float* values = (const float*)d_in[10];
    const float* imp    = (const float*)d_in[11];
    float* out = (float*)d_out;
    float* ws  = (float*)d_ws;

    // ws layout (floats):
    // [0,2048)      h1
    // [2048,5120)   comb = last_hidden (2048) | retrieved (1024)
    // [5120,6144)   q
    // [6144,9216)   cand_val (3072)
    // [9216,12288)  cand_idx (3072 ints)
    float* h1       = ws;
    float* comb     = ws + 2048;
    float* retr     = ws + 4096;
    float* q        = ws + 5120;
    float* cand_val = ws + 6144;
    int*   cand_idx = (int*)(ws + 9216);

    const float* xlast = x + (size_t)(4096 - 1) * 2048;  // only last position matters

    hipMemsetAsync(d_ws, 0, 6144 * sizeof(float), stream);   // atomic accumulators
    hipMemsetAsync(d_out, 0, (size_t)out_size * sizeof(float), stream);

    // h1 = xlast @ W1 + b1                       (16 MB)
    gemv_atomic4<0><<<dim3(2, 128), 256, 0, stream>>>(xlast, W1, b1, h1, 2048, 16);
    // last_hidden = relu(h1) @ W2 + b2           (16 MB)
    gemv_atomic4<1><<<dim3(2, 128), 256, 0, stream>>>(h1, W2, b2, comb, 2048, 16);
    // q = last_hidden @ Wq + bq                  (8 MB)
    gemv_atomic4<0><<<dim3(1, 128), 256, 0, stream>>>(comb, Wq, bq, q, 1024, 16);
    // sims + per-block top-3 over 65536 key rows (256 MB — dominant)
    sims_top3_pf<<<1024, 256, 0, stream>>>(q, keys, imp, cand_val, cand_idx);
    // global top-3 + softmax + values gather -> retrieved
    finalize_retrieve<<<1, 1024, 0, stream>>>(q, cand_val, cand_idx, values, retr);
    // out = comb @ Wout + bout                   (24 MB)
    gemv_atomic4<0><<<dim3(2, 128), 256, 0, stream>>>(comb, Wout, bout, out, 2048, 24);
}